// Round 10
// baseline (1289.309 us; speedup 1.0000x reference)
//
#include <hip/hip_runtime.h>

#define NN 50000
#define EE 1600000
#define NBA 65536   // B*A
#define KH 50

static __device__ __forceinline__ float clipf(float x, float lo, float hi) {
    return fminf(fmaxf(x, lo), hi);
}

// ---------------- CSR build (validated) ----------------

__global__ void k_degree(const int* __restrict__ dst, int* __restrict__ cnt, int E) {
    int i = blockIdx.x * blockDim.x + threadIdx.x;
    int stride = gridDim.x * blockDim.x;
    for (; i < E; i += stride) atomicAdd(&cnt[dst[i]], 1);
}

__global__ void k_scan1(const int* __restrict__ cnt, int* __restrict__ part,
                        int* __restrict__ bsum, int n) {
    __shared__ int sm[256];
    int t = threadIdx.x;
    int i = blockIdx.x * 256 + t;
    int v = (i < n) ? cnt[i] : 0;
    sm[t] = v; __syncthreads();
#pragma unroll
    for (int off = 1; off < 256; off <<= 1) {
        int u = (t >= off) ? sm[t - off] : 0;
        __syncthreads();
        sm[t] += u;
        __syncthreads();
    }
    if (i < n) part[i] = sm[t];
    if (t == 255) bsum[blockIdx.x] = sm[255];
}

__global__ void k_scan2(int* __restrict__ bsum, int nb) {
    __shared__ int sm[256];
    int t = threadIdx.x;
    int v = (t < nb) ? bsum[t] : 0;
    sm[t] = v; __syncthreads();
#pragma unroll
    for (int off = 1; off < 256; off <<= 1) {
        int u = (t >= off) ? sm[t - off] : 0;
        __syncthreads();
        sm[t] += u;
        __syncthreads();
    }
    if (t < nb) bsum[t] = sm[t];
}

__global__ void k_scan3(const int* __restrict__ cnt, const int* __restrict__ part,
                        const int* __restrict__ bsum, int* __restrict__ row_off,
                        int* __restrict__ cursor, int n) {
    int i = blockIdx.x * 256 + threadIdx.x;
    if (i >= n) return;
    int base = (blockIdx.x > 0) ? bsum[blockIdx.x - 1] : 0;
    int incl = part[i] + base;
    row_off[i + 1] = incl;
    cursor[i] = incl - cnt[i];
    if (i == 0) row_off[0] = 0;
}

__global__ void k_scatter(const int* __restrict__ src, const int* __restrict__ dst,
                          int* __restrict__ cursor, int* __restrict__ csr, int E) {
    int i = blockIdx.x * blockDim.x + threadIdx.x;
    int stride = gridDim.x * blockDim.x;
    for (; i < E; i += stride) {
        int d = dst[i];
        int p = atomicAdd(&cursor[d], 1);
        csr[p] = src[i];
    }
}

// ---------------- aggregation: wave per node, bd-identical serial-j f64 order ----------------

template <int DIN>
__global__ __launch_bounds__(256) void k5_agg(const float* __restrict__ hin,
                                              float* __restrict__ meanb,
                                              const int* __restrict__ row_off,
                                              const int* __restrict__ csr, int n) {
    int wave = threadIdx.x >> 6, lane = threadIdx.x & 63;
    int nw = (gridDim.x * blockDim.x) >> 6;
    for (int node = blockIdx.x * 4 + wave; node < n; node += nw) {
        int r0 = row_off[node], r1 = row_off[node + 1];
        if (lane < DIN) {
            double acc = 0.0;
#pragma unroll 4
            for (int j = r0; j < r1; ++j) {
                int s = csr[j];  // wave-uniform broadcast load
                acc += (double)hin[s * DIN + lane];
            }
            meanb[node * DIN + lane] = (float)(acc / fmax((double)(r1 - r0), 1.0));
        }
    }
}

// ---------------- SAGE transform: wave per node, bd-identical f64 arithmetic ----------------

template <int DIN>
__global__ __launch_bounds__(256) void k5_mat(const float* __restrict__ hin,
                                              const float* __restrict__ meanb,
                                              float* __restrict__ hout,
                                              const float* __restrict__ wl,
                                              const float* __restrict__ bl,
                                              const float* __restrict__ wr,
                                              const float* __restrict__ g,
                                              const float* __restrict__ b,
                                              const float* __restrict__ m,
                                              const float* __restrict__ v,
                                              int n, int isFinal) {
    __shared__ __align__(16) float s_in[4][2][DIN];
    int wave = threadIdx.x >> 6, lane = threadIdx.x & 63;
    float wlc[DIN], wrc[DIN];  // f32 register copies; converted to f64 at use
#pragma unroll
    for (int k = 0; k < DIN; ++k) {
        wlc[k] = wl[k * 64 + lane];
        wrc[k] = wr[k * 64 + lane];
    }
    double bl_d = (double)bl[lane];
    double m_c = (double)m[lane], g_c = (double)g[lane], b_c = (double)b[lane];
    double rsq = 1.0 / sqrt((double)v[lane] + 1e-5);
    int nw = (gridDim.x * blockDim.x) >> 6;
    for (int node = blockIdx.x * 4 + wave; node < n; node += nw) {
        if (lane < DIN) {
            s_in[wave][0][lane] = meanb[node * DIN + lane];
            s_in[wave][1][lane] = hin[node * DIN + lane];
        }
        // wave-private LDS slice: write->read within one wave, no barrier needed
        double out = bl_d;
#pragma unroll 8
        for (int k = 0; k < DIN; ++k)
            out += (double)s_in[wave][0][k] * (double)wlc[k] +
                   (double)s_in[wave][1][k] * (double)wrc[k];
        double ss = out * out;
#pragma unroll
        for (int i = 32; i >= 1; i >>= 1) ss += __shfl_xor(ss, i);
        double nrm = fmax(sqrt(ss), 1e-12);
        double o = out / nrm;
        double y = ((o - m_c) * rsq) * g_c + b_c;
        y = fmax(y, 0.0);
        if (isFinal) y = fmin(y, 5.0);
        hout[node * 64 + lane] = (float)y;
    }
}

// ---------------- placement head (R2-validated f32 structure) ----------------

__global__ __launch_bounds__(256) void k_place(const float* __restrict__ ne,
                                               const float* __restrict__ w1,
                                               const float* __restrict__ b1,
                                               const float* __restrict__ g,
                                               const float* __restrict__ b,
                                               const float* __restrict__ m,
                                               const float* __restrict__ v,
                                               const float* __restrict__ w2,
                                               const float* __restrict__ b2,
                                               float* __restrict__ out, int n) {
    __shared__ __align__(16) float s_w1[64 * 32];
    __shared__ __align__(16) float s_row[4][64];
    for (int i = threadIdx.x; i < 64 * 32; i += 256) s_w1[i] = w1[i];
    __syncthreads();
    int wave = threadIdx.x >> 6, lane = threadIdx.x & 63;
    int c = lane & 31;
    float b1_c = b1[c], w2_c = w2[c], b2v = b2[0];
    float scale = g[c] * rsqrtf(v[c] + 1e-5f);
    float shift = b[c] - m[c] * scale;
    int nw = (gridDim.x * blockDim.x) >> 6;
    for (int node = blockIdx.x * 4 + wave; node < n; node += nw) {
        s_row[wave][lane] = ne[node * 64 + lane];
        int k0 = (lane >> 5) * 32;  // half-wave splits k range
        float acc = 0.f;
#pragma unroll
        for (int kk = 0; kk < 32; kk += 4) {
            int k = k0 + kk;
            float4 rv = *(const float4*)&s_row[wave][k];
            acc += rv.x * s_w1[k * 32 + c] + rv.y * s_w1[(k + 1) * 32 + c] +
                   rv.z * s_w1[(k + 2) * 32 + c] + rv.w * s_w1[(k + 3) * 32 + c];
        }
        acc += __shfl_xor(acc, 32);
        float h = fmaxf((acc + b1_c) * scale + shift, 0.f);
        float p = h * w2_c;
#pragma unroll
        for (int i = 16; i >= 1; i >>= 1) p += __shfl_xor(p, i);
        if (lane == 0) out[node] = clipf(p + b2v, -15.f, 15.f);
    }
}

// ---------------- attack head: wave/4 edges, weights via L1 (no LDS staging), f32 ----------------

__global__ __launch_bounds__(256, 4) void k6_attack(const float* __restrict__ ne,
                                                    const int* __restrict__ ae,
                                                    const int* __restrict__ mask,
                                                    const float* __restrict__ w1,
                                                    const float* __restrict__ b1,
                                                    const float* __restrict__ g,
                                                    const float* __restrict__ b,
                                                    const float* __restrict__ m,
                                                    const float* __restrict__ v,
                                                    const float* __restrict__ w2,
                                                    const float* __restrict__ b2,
                                                    float* __restrict__ out, int nE) {
    __shared__ __align__(16) float s_ee[4][4][128];
    int wave = threadIdx.x >> 6, lane = threadIdx.x & 63;
    float b1_c = b1[lane];
    double scd = (double)g[lane] / sqrt((double)v[lane] + 1e-5);
    float scale = (float)scd;
    float shift = (float)((double)b[lane] - (double)m[lane] * scd);
    float w2_c = w2[lane], b2v = b2[0];
    int nwaves = (gridDim.x * blockDim.x) >> 6;
    for (int e0 = (blockIdx.x * 4 + wave) * 4; e0 < nE; e0 += nwaves * 4) {
#pragma unroll
        for (int q = 0; q < 4; ++q) {
            int e = min(e0 + q, nE - 1);
            int s = min(max(ae[e * 2 + 0], 0), NN - 1);
            int t = min(max(ae[e * 2 + 1], 0), NN - 1);
            s_ee[wave][q][lane] = clipf(ne[s * 64 + lane], -3.f, 3.f);
            s_ee[wave][q][64 + lane] = clipf(ne[t * 64 + lane], -3.f, 3.f);
        }
        float a[4] = {b1_c, b1_c, b1_c, b1_c};
#pragma unroll 2
        for (int k0 = 0; k0 < 128; k0 += 2) {
            float w_0 = w1[(k0 + 0) * 64 + lane];
            float w_1 = w1[(k0 + 1) * 64 + lane];
#pragma unroll
            for (int q = 0; q < 4; ++q) {
                float e0v = s_ee[wave][q][k0 + 0];
                float e1v = s_ee[wave][q][k0 + 1];
                a[q] = fmaf(e0v, w_0, a[q]);
                a[q] = fmaf(e1v, w_1, a[q]);
            }
        }
#pragma unroll
        for (int q = 0; q < 4; ++q) {
            float y = fmaxf(fmaf(a[q], scale, shift), 0.f);
            float p = y * w2_c;
#pragma unroll
            for (int i = 32; i >= 1; i >>= 1) p += __shfl_xor(p, i);
            int e = e0 + q;
            if (lane == 0 && e < nE) {
                float logit = clipf(p + b2v, -15.f, 15.f);
                out[e] = mask[e] ? logit : -1e9f;
            }
        }
    }
}

// ---------------- army head: wave/4 edges, weights via L1, f64 (k3-identical order) ----------------

__global__ __launch_bounds__(256, 4) void k6_army(const float* __restrict__ ne,
                                                  const int* __restrict__ ae,
                                                  const int* __restrict__ mask,
                                                  const float* __restrict__ w1,
                                                  const float* __restrict__ b1,
                                                  const float* __restrict__ g,
                                                  const float* __restrict__ b,
                                                  const float* __restrict__ m,
                                                  const float* __restrict__ v,
                                                  const float* __restrict__ w2,
                                                  const float* __restrict__ b2,
                                                  float* __restrict__ out, int nE) {
    __shared__ __align__(16) float s_ee[4][4][128];
    __shared__ __align__(16) double s_h[4][4][64];
    int wave = threadIdx.x >> 6, lane = threadIdx.x & 63;
    double b1_c = (double)b1[lane];
    double m_c = (double)m[lane], g_c = (double)g[lane], b_c = (double)b[lane];
    double rsq = 1.0 / sqrt((double)v[lane] + 1e-5);
    double b2_k = (lane < KH) ? (double)b2[lane] : 0.0;
    int nwaves = (gridDim.x * blockDim.x) >> 6;
    for (int e0 = (blockIdx.x * 4 + wave) * 4; e0 < nE; e0 += nwaves * 4) {
#pragma unroll
        for (int q = 0; q < 4; ++q) {
            int e = min(e0 + q, nE - 1);
            int s = min(max(ae[e * 2 + 0], 0), NN - 1);
            int t = min(max(ae[e * 2 + 1], 0), NN - 1);
            s_ee[wave][q][lane] = clipf(ne[s * 64 + lane], -3.f, 3.f);
            s_ee[wave][q][64 + lane] = clipf(ne[t * 64 + lane], -3.f, 3.f);
        }
        double a[4] = {b1_c, b1_c, b1_c, b1_c};
#pragma unroll 2
        for (int k0 = 0; k0 < 128; k0 += 2) {
            double w_0 = (double)w1[(k0 + 0) * 64 + lane];
            double w_1 = (double)w1[(k0 + 1) * 64 + lane];
#pragma unroll
            for (int q = 0; q < 4; ++q) {
                float e0v = s_ee[wave][q][k0 + 0];
                float e1v = s_ee[wave][q][k0 + 1];
                a[q] += (double)e0v * w_0;
                a[q] += (double)e1v * w_1;
            }
        }
#pragma unroll
        for (int q = 0; q < 4; ++q) {
            double hR = ((a[q] - m_c) * rsq) * g_c + b_c;
            s_h[wave][q][lane] = fmax(hR, 0.0);
        }
        double acc2[4] = {b2_k, b2_k, b2_k, b2_k};
        for (int j = 0; j < 64; ++j) {
            double w2j = (lane < KH) ? (double)w2[j * KH + lane] : 0.0;
#pragma unroll
            for (int q = 0; q < 4; ++q) acc2[q] += s_h[wave][q][j] * w2j;
        }
#pragma unroll
        for (int q = 0; q < 4; ++q) {
            int e = e0 + q;
            if (lane < KH && e < nE) {
                float logit = (float)fmin(fmax(acc2[q], -15.0), 15.0);
                out[e * KH + lane] = mask[e] ? logit : -1e9f;
            }
        }
    }
}

// ---------------- launch ----------------

extern "C" void kernel_launch(void* const* d_in, const int* in_sizes, int n_in,
                              void* d_out, int out_size, void* d_ws, size_t ws_size,
                              hipStream_t stream) {
    const float* x = (const float*)d_in[0];
    const int* ei = (const int*)d_in[1];
    const int* ae = (const int*)d_in[2];
    const int* mask = (const int*)d_in[4];   // jnp.bool_ arrives as int32
    const float *s1_wl = (const float*)d_in[5], *s1_bl = (const float*)d_in[6],
                *s1_wr = (const float*)d_in[7], *s1_g = (const float*)d_in[8],
                *s1_b = (const float*)d_in[9], *s1_m = (const float*)d_in[10],
                *s1_v = (const float*)d_in[11];
    const float *s2_wl = (const float*)d_in[12], *s2_bl = (const float*)d_in[13],
                *s2_wr = (const float*)d_in[14], *s2_g = (const float*)d_in[15],
                *s2_b = (const float*)d_in[16], *s2_m = (const float*)d_in[17],
                *s2_v = (const float*)d_in[18];
    const float *s3_wl = (const float*)d_in[19], *s3_bl = (const float*)d_in[20],
                *s3_wr = (const float*)d_in[21], *s3_g = (const float*)d_in[22],
                *s3_b = (const float*)d_in[23], *s3_m = (const float*)d_in[24],
                *s3_v = (const float*)d_in[25];
    const float *pl_w1 = (const float*)d_in[26], *pl_b1 = (const float*)d_in[27],
                *pl_g = (const float*)d_in[28], *pl_b = (const float*)d_in[29],
                *pl_m = (const float*)d_in[30], *pl_v = (const float*)d_in[31],
                *pl_w2 = (const float*)d_in[32], *pl_b2 = (const float*)d_in[33];
    const float *es_w1 = (const float*)d_in[34], *es_b1 = (const float*)d_in[35],
                *es_g = (const float*)d_in[36], *es_b = (const float*)d_in[37],
                *es_m = (const float*)d_in[38], *es_v = (const float*)d_in[39],
                *es_w2 = (const float*)d_in[40], *es_b2 = (const float*)d_in[41];
    const float *as_w1 = (const float*)d_in[42], *as_b1 = (const float*)d_in[43],
                *as_g = (const float*)d_in[44], *as_b = (const float*)d_in[45],
                *as_m = (const float*)d_in[46], *as_v = (const float*)d_in[47],
                *as_w2 = (const float*)d_in[48], *as_b2 = (const float*)d_in[49];

    // workspace carve-up (~45 MB)
    char* w = (char*)d_ws;
    size_t off = 0;
    auto carve = [&](size_t bytes) {
        char* p = w + off;
        off = (off + bytes + 255) & ~(size_t)255;
        return p;
    };
    int* cnt = (int*)carve(NN * 4);
    int* part = (int*)carve(NN * 4);
    int* bsum = (int*)carve(256 * 4);
    int* row_off = (int*)carve((NN + 1) * 4);
    int* cursor = (int*)carve(NN * 4);
    int* csr = (int*)carve((size_t)EE * 4);
    float* meanb = (float*)carve((size_t)NN * 64 * 4);
    float* hA = (float*)carve((size_t)NN * 64 * 4);
    float* hB = (float*)carve((size_t)NN * 64 * 4);

    const int* src_g = ei;       // edge_index[0]
    const int* dst_g = ei + EE;  // edge_index[1]
    int nscan = (NN + 255) / 256;  // 196

    hipMemsetAsync(cnt, 0, NN * 4, stream);
    k_degree<<<1024, 256, 0, stream>>>(dst_g, cnt, EE);
    k_scan1<<<nscan, 256, 0, stream>>>(cnt, part, bsum, NN);
    k_scan2<<<1, 256, 0, stream>>>(bsum, nscan);
    k_scan3<<<nscan, 256, 0, stream>>>(cnt, part, bsum, row_off, cursor, NN);
    k_scatter<<<1024, 256, 0, stream>>>(src_g, dst_g, cursor, csr, EE);

    // layer 1: x(32,f32) -> hA(64,f32)
    k5_agg<32><<<2048, 256, 0, stream>>>(x, meanb, row_off, csr, NN);
    k5_mat<32><<<2048, 256, 0, stream>>>(x, meanb, hA, s1_wl, s1_bl, s1_wr,
                                         s1_g, s1_b, s1_m, s1_v, NN, 0);
    // layer 2: hA -> hB
    k5_agg<64><<<2048, 256, 0, stream>>>(hA, meanb, row_off, csr, NN);
    k5_mat<64><<<2048, 256, 0, stream>>>(hA, meanb, hB, s2_wl, s2_bl, s2_wr,
                                         s2_g, s2_b, s2_m, s2_v, NN, 0);
    // layer 3: hB -> hA (= ne)
    k5_agg<64><<<2048, 256, 0, stream>>>(hB, meanb, row_off, csr, NN);
    k5_mat<64><<<2048, 256, 0, stream>>>(hB, meanb, hA, s3_wl, s3_bl, s3_wr,
                                         s3_g, s3_b, s3_m, s3_v, NN, 1);
    const float* ne = hA;

    float* out_place = (float*)d_out;
    float* out_attack = out_place + NN;
    float* out_army = out_attack + NBA;

    k_place<<<2048, 256, 0, stream>>>(ne, pl_w1, pl_b1, pl_g, pl_b, pl_m, pl_v,
                                      pl_w2, pl_b2, out_place, NN);
    k6_attack<<<2048, 256, 0, stream>>>(ne, ae, mask, es_w1, es_b1, es_g, es_b,
                                        es_m, es_v, es_w2, es_b2, out_attack, NBA);
    k6_army<<<2048, 256, 0, stream>>>(ne, ae, mask, as_w1, as_b1, as_g, as_b,
                                      as_m, as_v, as_w2, as_b2, out_army, NBA);
}

// Round 11
// 894.936 us; speedup vs baseline: 1.4407x; 1.4407x over previous
//
#include <hip/hip_runtime.h>

#define NN 50000
#define EE 1600000
#define NBA 65536   // B*A
#define KH 50

static __device__ __forceinline__ float clipf(float x, float lo, float hi) {
    return fminf(fmaxf(x, lo), hi);
}

// ---------------- CSR build (validated) ----------------

__global__ void k_degree(const int* __restrict__ dst, int* __restrict__ cnt, int E) {
    int i = blockIdx.x * blockDim.x + threadIdx.x;
    int stride = gridDim.x * blockDim.x;
    for (; i < E; i += stride) atomicAdd(&cnt[dst[i]], 1);
}

__global__ void k_scan1(const int* __restrict__ cnt, int* __restrict__ part,
                        int* __restrict__ bsum, int n) {
    __shared__ int sm[256];
    int t = threadIdx.x;
    int i = blockIdx.x * 256 + t;
    int v = (i < n) ? cnt[i] : 0;
    sm[t] = v; __syncthreads();
#pragma unroll
    for (int off = 1; off < 256; off <<= 1) {
        int u = (t >= off) ? sm[t - off] : 0;
        __syncthreads();
        sm[t] += u;
        __syncthreads();
    }
    if (i < n) part[i] = sm[t];
    if (t == 255) bsum[blockIdx.x] = sm[255];
}

__global__ void k_scan2(int* __restrict__ bsum, int nb) {
    __shared__ int sm[256];
    int t = threadIdx.x;
    int v = (t < nb) ? bsum[t] : 0;
    sm[t] = v; __syncthreads();
#pragma unroll
    for (int off = 1; off < 256; off <<= 1) {
        int u = (t >= off) ? sm[t - off] : 0;
        __syncthreads();
        sm[t] += u;
        __syncthreads();
    }
    if (t < nb) bsum[t] = sm[t];
}

__global__ void k_scan3(const int* __restrict__ cnt, const int* __restrict__ part,
                        const int* __restrict__ bsum, int* __restrict__ row_off,
                        int* __restrict__ cursor, int n) {
    int i = blockIdx.x * 256 + threadIdx.x;
    if (i >= n) return;
    int base = (blockIdx.x > 0) ? bsum[blockIdx.x - 1] : 0;
    int incl = part[i] + base;
    row_off[i + 1] = incl;
    cursor[i] = incl - cnt[i];
    if (i == 0) row_off[0] = 0;
}

__global__ void k_scatter(const int* __restrict__ src, const int* __restrict__ dst,
                          int* __restrict__ cursor, int* __restrict__ csr, int E) {
    int i = blockIdx.x * blockDim.x + threadIdx.x;
    int stride = gridDim.x * blockDim.x;
    for (; i < E; i += stride) {
        int d = dst[i];
        int p = atomicAdd(&cursor[d], 1);
        csr[p] = src[i];
    }
}

// ---------------- aggregation: wave per node, serial-j f64 order (R10-validated) ----------------

template <int DIN>
__global__ __launch_bounds__(256) void k5_agg(const float* __restrict__ hin,
                                              float* __restrict__ meanb,
                                              const int* __restrict__ row_off,
                                              const int* __restrict__ csr, int n) {
    int wave = threadIdx.x >> 6, lane = threadIdx.x & 63;
    int nw = (gridDim.x * blockDim.x) >> 6;
    for (int node = blockIdx.x * 4 + wave; node < n; node += nw) {
        int r0 = row_off[node], r1 = row_off[node + 1];
        if (lane < DIN) {
            double acc = 0.0;
#pragma unroll 4
            for (int j = r0; j < r1; ++j) {
                int s = csr[j];  // wave-uniform broadcast load
                acc += (double)hin[s * DIN + lane];
            }
            meanb[node * DIN + lane] = (float)(acc / fmax((double)(r1 - r0), 1.0));
        }
    }
}

// ---------------- SAGE transform: wave per node, f64, FULL unroll (weights in VGPRs) ----------------

template <int DIN>
__global__ __launch_bounds__(256) void k5_mat(const float* __restrict__ hin,
                                              const float* __restrict__ meanb,
                                              float* __restrict__ hout,
                                              const float* __restrict__ wl,
                                              const float* __restrict__ bl,
                                              const float* __restrict__ wr,
                                              const float* __restrict__ g,
                                              const float* __restrict__ b,
                                              const float* __restrict__ m,
                                              const float* __restrict__ v,
                                              int n, int isFinal) {
    __shared__ __align__(16) float s_in[4][2][DIN];
    int wave = threadIdx.x >> 6, lane = threadIdx.x & 63;
    float wlc[DIN], wrc[DIN];  // MUST stay in VGPRs: all accesses below are compile-time-indexed
#pragma unroll
    for (int k = 0; k < DIN; ++k) {
        wlc[k] = wl[k * 64 + lane];
        wrc[k] = wr[k * 64 + lane];
    }
    double bl_d = (double)bl[lane];
    double m_c = (double)m[lane], g_c = (double)g[lane], b_c = (double)b[lane];
    double rsq = 1.0 / sqrt((double)v[lane] + 1e-5);
    int nw = (gridDim.x * blockDim.x) >> 6;
    for (int node = blockIdx.x * 4 + wave; node < n; node += nw) {
        if (lane < DIN) {
            s_in[wave][0][lane] = meanb[node * DIN + lane];
            s_in[wave][1][lane] = hin[node * DIN + lane];
        }
        // wave-private LDS slice: write->read within one wave, no barrier needed
        double out = bl_d;
#pragma unroll
        for (int k = 0; k < DIN; ++k)
            out += (double)s_in[wave][0][k] * (double)wlc[k] +
                   (double)s_in[wave][1][k] * (double)wrc[k];
        double ss = out * out;
#pragma unroll
        for (int i = 32; i >= 1; i >>= 1) ss += __shfl_xor(ss, i);
        double nrm = fmax(sqrt(ss), 1e-12);
        double o = out / nrm;
        double y = ((o - m_c) * rsq) * g_c + b_c;
        y = fmax(y, 0.0);
        if (isFinal) y = fmin(y, 5.0);
        hout[node * 64 + lane] = (float)y;
    }
}

// ---------------- placement head (R2-validated f32 structure) ----------------

__global__ __launch_bounds__(256) void k_place(const float* __restrict__ ne,
                                               const float* __restrict__ w1,
                                               const float* __restrict__ b1,
                                               const float* __restrict__ g,
                                               const float* __restrict__ b,
                                               const float* __restrict__ m,
                                               const float* __restrict__ v,
                                               const float* __restrict__ w2,
                                               const float* __restrict__ b2,
                                               float* __restrict__ out, int n) {
    __shared__ __align__(16) float s_w1[64 * 32];
    __shared__ __align__(16) float s_row[4][64];
    for (int i = threadIdx.x; i < 64 * 32; i += 256) s_w1[i] = w1[i];
    __syncthreads();
    int wave = threadIdx.x >> 6, lane = threadIdx.x & 63;
    int c = lane & 31;
    float b1_c = b1[c], w2_c = w2[c], b2v = b2[0];
    float scale = g[c] * rsqrtf(v[c] + 1e-5f);
    float shift = b[c] - m[c] * scale;
    int nw = (gridDim.x * blockDim.x) >> 6;
    for (int node = blockIdx.x * 4 + wave; node < n; node += nw) {
        s_row[wave][lane] = ne[node * 64 + lane];
        int k0 = (lane >> 5) * 32;  // half-wave splits k range
        float acc = 0.f;
#pragma unroll
        for (int kk = 0; kk < 32; kk += 4) {
            int k = k0 + kk;
            float4 rv = *(const float4*)&s_row[wave][k];
            acc += rv.x * s_w1[k * 32 + c] + rv.y * s_w1[(k + 1) * 32 + c] +
                   rv.z * s_w1[(k + 2) * 32 + c] + rv.w * s_w1[(k + 3) * 32 + c];
        }
        acc += __shfl_xor(acc, 32);
        float h = fmaxf((acc + b1_c) * scale + shift, 0.f);
        float p = h * w2_c;
#pragma unroll
        for (int i = 16; i >= 1; i >>= 1) p += __shfl_xor(p, i);
        if (lane == 0) out[node] = clipf(p + b2v, -15.f, 15.f);
    }
}

// ---------------- attack head: wave/4 edges, weights via L1 (R10-validated) ----------------

__global__ __launch_bounds__(256, 4) void k6_attack(const float* __restrict__ ne,
                                                    const int* __restrict__ ae,
                                                    const int* __restrict__ mask,
                                                    const float* __restrict__ w1,
                                                    const float* __restrict__ b1,
                                                    const float* __restrict__ g,
                                                    const float* __restrict__ b,
                                                    const float* __restrict__ m,
                                                    const float* __restrict__ v,
                                                    const float* __restrict__ w2,
                                                    const float* __restrict__ b2,
                                                    float* __restrict__ out, int nE) {
    __shared__ __align__(16) float s_ee[4][4][128];
    int wave = threadIdx.x >> 6, lane = threadIdx.x & 63;
    float b1_c = b1[lane];
    double scd = (double)g[lane] / sqrt((double)v[lane] + 1e-5);
    float scale = (float)scd;
    float shift = (float)((double)b[lane] - (double)m[lane] * scd);
    float w2_c = w2[lane], b2v = b2[0];
    int nwaves = (gridDim.x * blockDim.x) >> 6;
    for (int e0 = (blockIdx.x * 4 + wave) * 4; e0 < nE; e0 += nwaves * 4) {
#pragma unroll
        for (int q = 0; q < 4; ++q) {
            int e = min(e0 + q, nE - 1);
            int s = min(max(ae[e * 2 + 0], 0), NN - 1);
            int t = min(max(ae[e * 2 + 1], 0), NN - 1);
            s_ee[wave][q][lane] = clipf(ne[s * 64 + lane], -3.f, 3.f);
            s_ee[wave][q][64 + lane] = clipf(ne[t * 64 + lane], -3.f, 3.f);
        }
        float a[4] = {b1_c, b1_c, b1_c, b1_c};
#pragma unroll 2
        for (int k0 = 0; k0 < 128; k0 += 2) {
            float w_0 = w1[(k0 + 0) * 64 + lane];
            float w_1 = w1[(k0 + 1) * 64 + lane];
#pragma unroll
            for (int q = 0; q < 4; ++q) {
                float e0v = s_ee[wave][q][k0 + 0];
                float e1v = s_ee[wave][q][k0 + 1];
                a[q] = fmaf(e0v, w_0, a[q]);
                a[q] = fmaf(e1v, w_1, a[q]);
            }
        }
#pragma unroll
        for (int q = 0; q < 4; ++q) {
            float y = fmaxf(fmaf(a[q], scale, shift), 0.f);
            float p = y * w2_c;
#pragma unroll
            for (int i = 32; i >= 1; i >>= 1) p += __shfl_xor(p, i);
            int e = e0 + q;
            if (lane == 0 && e < nE) {
                float logit = clipf(p + b2v, -15.f, 15.f);
                out[e] = mask[e] ? logit : -1e9f;
            }
        }
    }
}

// ---------------- army head: wave/4 edges, weights via L1, f64 (R10-validated) ----------------

__global__ __launch_bounds__(256, 4) void k6_army(const float* __restrict__ ne,
                                                  const int* __restrict__ ae,
                                                  const int* __restrict__ mask,
                                                  const float* __restrict__ w1,
                                                  const float* __restrict__ b1,
                                                  const float* __restrict__ g,
                                                  const float* __restrict__ b,
                                                  const float* __restrict__ m,
                                                  const float* __restrict__ v,
                                                  const float* __restrict__ w2,
                                                  const float* __restrict__ b2,
                                                  float* __restrict__ out, int nE) {
    __shared__ __align__(16) float s_ee[4][4][128];
    __shared__ __align__(16) double s_h[4][4][64];
    int wave = threadIdx.x >> 6, lane = threadIdx.x & 63;
    double b1_c = (double)b1[lane];
    double m_c = (double)m[lane], g_c = (double)g[lane], b_c = (double)b[lane];
    double rsq = 1.0 / sqrt((double)v[lane] + 1e-5);
    double b2_k = (lane < KH) ? (double)b2[lane] : 0.0;
    int nwaves = (gridDim.x * blockDim.x) >> 6;
    for (int e0 = (blockIdx.x * 4 + wave) * 4; e0 < nE; e0 += nwaves * 4) {
#pragma unroll
        for (int q = 0; q < 4; ++q) {
            int e = min(e0 + q, nE - 1);
            int s = min(max(ae[e * 2 + 0], 0), NN - 1);
            int t = min(max(ae[e * 2 + 1], 0), NN - 1);
            s_ee[wave][q][lane] = clipf(ne[s * 64 + lane], -3.f, 3.f);
            s_ee[wave][q][64 + lane] = clipf(ne[t * 64 + lane], -3.f, 3.f);
        }
        double a[4] = {b1_c, b1_c, b1_c, b1_c};
#pragma unroll 2
        for (int k0 = 0; k0 < 128; k0 += 2) {
            double w_0 = (double)w1[(k0 + 0) * 64 + lane];
            double w_1 = (double)w1[(k0 + 1) * 64 + lane];
#pragma unroll
            for (int q = 0; q < 4; ++q) {
                float e0v = s_ee[wave][q][k0 + 0];
                float e1v = s_ee[wave][q][k0 + 1];
                a[q] += (double)e0v * w_0;
                a[q] += (double)e1v * w_1;
            }
        }
#pragma unroll
        for (int q = 0; q < 4; ++q) {
            double hR = ((a[q] - m_c) * rsq) * g_c + b_c;
            s_h[wave][q][lane] = fmax(hR, 0.0);
        }
        double acc2[4] = {b2_k, b2_k, b2_k, b2_k};
        for (int j = 0; j < 64; ++j) {
            double w2j = (lane < KH) ? (double)w2[j * KH + lane] : 0.0;
#pragma unroll
            for (int q = 0; q < 4; ++q) acc2[q] += s_h[wave][q][j] * w2j;
        }
#pragma unroll
        for (int q = 0; q < 4; ++q) {
            int e = e0 + q;
            if (lane < KH && e < nE) {
                float logit = (float)fmin(fmax(acc2[q], -15.0), 15.0);
                out[e * KH + lane] = mask[e] ? logit : -1e9f;
            }
        }
    }
}

// ---------------- launch ----------------

extern "C" void kernel_launch(void* const* d_in, const int* in_sizes, int n_in,
                              void* d_out, int out_size, void* d_ws, size_t ws_size,
                              hipStream_t stream) {
    const float* x = (const float*)d_in[0];
    const int* ei = (const int*)d_in[1];
    const int* ae = (const int*)d_in[2];
    const int* mask = (const int*)d_in[4];   // jnp.bool_ arrives as int32
    const float *s1_wl = (const float*)d_in[5], *s1_bl = (const float*)d_in[6],
                *s1_wr = (const float*)d_in[7], *s1_g = (const float*)d_in[8],
                *s1_b = (const float*)d_in[9], *s1_m = (const float*)d_in[10],
                *s1_v = (const float*)d_in[11];
    const float *s2_wl = (const float*)d_in[12], *s2_bl = (const float*)d_in[13],
                *s2_wr = (const float*)d_in[14], *s2_g = (const float*)d_in[15],
                *s2_b = (const float*)d_in[16], *s2_m = (const float*)d_in[17],
                *s2_v = (const float*)d_in[18];
    const float *s3_wl = (const float*)d_in[19], *s3_bl = (const float*)d_in[20],
                *s3_wr = (const float*)d_in[21], *s3_g = (const float*)d_in[22],
                *s3_b = (const float*)d_in[23], *s3_m = (const float*)d_in[24],
                *s3_v = (const float*)d_in[25];
    const float *pl_w1 = (const float*)d_in[26], *pl_b1 = (const float*)d_in[27],
                *pl_g = (const float*)d_in[28], *pl_b = (const float*)d_in[29],
                *pl_m = (const float*)d_in[30], *pl_v = (const float*)d_in[31],
                *pl_w2 = (const float*)d_in[32], *pl_b2 = (const float*)d_in[33];
    const float *es_w1 = (const float*)d_in[34], *es_b1 = (const float*)d_in[35],
                *es_g = (const float*)d_in[36], *es_b = (const float*)d_in[37],
                *es_m = (const float*)d_in[38], *es_v = (const float*)d_in[39],
                *es_w2 = (const float*)d_in[40], *es_b2 = (const float*)d_in[41];
    const float *as_w1 = (const float*)d_in[42], *as_b1 = (const float*)d_in[43],
                *as_g = (const float*)d_in[44], *as_b = (const float*)d_in[45],
                *as_m = (const float*)d_in[46], *as_v = (const float*)d_in[47],
                *as_w2 = (const float*)d_in[48], *as_b2 = (const float*)d_in[49];

    // workspace carve-up (~45 MB)
    char* w = (char*)d_ws;
    size_t off = 0;
    auto carve = [&](size_t bytes) {
        char* p = w + off;
        off = (off + bytes + 255) & ~(size_t)255;
        return p;
    };
    int* cnt = (int*)carve(NN * 4);
    int* part = (int*)carve(NN * 4);
    int* bsum = (int*)carve(256 * 4);
    int* row_off = (int*)carve((NN + 1) * 4);
    int* cursor = (int*)carve(NN * 4);
    int* csr = (int*)carve((size_t)EE * 4);
    float* meanb = (float*)carve((size_t)NN * 64 * 4);
    float* hA = (float*)carve((size_t)NN * 64 * 4);
    float* hB = (float*)carve((size_t)NN * 64 * 4);

    const int* src_g = ei;       // edge_index[0]
    const int* dst_g = ei + EE;  // edge_index[1]
    int nscan = (NN + 255) / 256;  // 196

    hipMemsetAsync(cnt, 0, NN * 4, stream);
    k_degree<<<1024, 256, 0, stream>>>(dst_g, cnt, EE);
    k_scan1<<<nscan, 256, 0, stream>>>(cnt, part, bsum, NN);
    k_scan2<<<1, 256, 0, stream>>>(bsum, nscan);
    k_scan3<<<nscan, 256, 0, stream>>>(cnt, part, bsum, row_off, cursor, NN);
    k_scatter<<<1024, 256, 0, stream>>>(src_g, dst_g, cursor, csr, EE);

    // layer 1: x(32,f32) -> hA(64,f32)
    k5_agg<32><<<2048, 256, 0, stream>>>(x, meanb, row_off, csr, NN);
    k5_mat<32><<<2048, 256, 0, stream>>>(x, meanb, hA, s1_wl, s1_bl, s1_wr,
                                         s1_g, s1_b, s1_m, s1_v, NN, 0);
    // layer 2: hA -> hB
    k5_agg<64><<<2048, 256, 0, stream>>>(hA, meanb, row_off, csr, NN);
    k5_mat<64><<<2048, 256, 0, stream>>>(hA, meanb, hB, s2_wl, s2_bl, s2_wr,
                                         s2_g, s2_b, s2_m, s2_v, NN, 0);
    // layer 3: hB -> hA (= ne)
    k5_agg<64><<<2048, 256, 0, stream>>>(hB, meanb, row_off, csr, NN);
    k5_mat<64><<<2048, 256, 0, stream>>>(hB, meanb, hA, s3_wl, s3_bl, s3_wr,
                                         s3_g, s3_b, s3_m, s3_v, NN, 1);
    const float* ne = hA;

    float* out_place = (float*)d_out;
    float* out_attack = out_place + NN;
    float* out_army = out_attack + NBA;

    k_place<<<2048, 256, 0, stream>>>(ne, pl_w1, pl_b1, pl_g, pl_b, pl_m, pl_v,
                                      pl_w2, pl_b2, out_place, NN);
    k6_attack<<<2048, 256, 0, stream>>>(ne, ae, mask, es_w1, es_b1, es_g, es_b,
                                        es_m, es_v, es_w2, es_b2, out_attack, NBA);
    k6_army<<<2048, 256, 0, stream>>>(ne, ae, mask, as_w1, as_b1, as_g, as_b,
                                      as_m, as_v, as_w2, as_b2, out_army, NBA);
}